// Round 3
// baseline (807.951 us; speedup 1.0000x reference)
//
#include <hip/hip_runtime.h>
#include <hip/hip_bf16.h>
#include <stdint.h>

typedef __bf16 bf16_t;
typedef __bf16 bf16x8 __attribute__((ext_vector_type(8)));
typedef float f32x4 __attribute__((ext_vector_type(4)));
typedef float f32x16 __attribute__((ext_vector_type(16)));

#define BB 4
#define NN 4096
#define DD 384
#define KBLK 64
#define NT (NN / KBLK)             // 64 kv tiles of 64 keys
#define NROWS (BB * NN)            // 16384
#define SCALEC 20.609929155556627f // log2(e)/0.07 ; also the fixed softmax max

// ---------------- Kernel 1: row-normalize -> bf16 ----------------
__global__ __launch_bounds__(256) void norm_kernel(const float* __restrict__ x,
                                                   bf16_t* __restrict__ xn) {
    int row  = blockIdx.x * 4 + (threadIdx.x >> 6);
    int lane = threadIdx.x & 63;
    const float* xr = x + (size_t)row * DD;
    float v[6];
    float ss = 0.f;
#pragma unroll
    for (int j = 0; j < 6; ++j) { v[j] = xr[lane + j * 64]; ss += v[j] * v[j]; }
#pragma unroll
    for (int m = 1; m < 64; m <<= 1) ss += __shfl_xor(ss, m);
    float inv = 1.0f / fmaxf(sqrtf(ss), 1e-12f);
    bf16_t* o = xn + (size_t)row * DD;
#pragma unroll
    for (int j = 0; j < 6; ++j) o[lane + j * 64] = (bf16_t)(v[j] * inv);
}

// ---------------- Kernel 2: transpose-cast x -> xvT (B, D, N) bf16 ----------------
__global__ __launch_bounds__(256) void transpose_kernel(const float* __restrict__ x,
                                                        bf16_t* __restrict__ xvT) {
    int bid = blockIdx.x;
    int dt = bid % (DD / 64);                 // 6
    int nt = (bid / (DD / 64)) % (NN / 64);   // 64
    int b  = bid / ((DD / 64) * (NN / 64));
    __shared__ float tile[64][65];
    int t = threadIdx.x;
    const float* src = x + ((size_t)b * NN + (size_t)nt * 64) * DD + dt * 64;
#pragma unroll
    for (int j = 0; j < 4; ++j) {
        int lin = j * 256 + t;
        int nl = lin >> 4;
        int dc = (lin & 15) * 4;
        const float4 f = *(const float4*)(src + (size_t)nl * DD + dc);
        tile[nl][dc + 0] = f.x; tile[nl][dc + 1] = f.y;
        tile[nl][dc + 2] = f.z; tile[nl][dc + 3] = f.w;
    }
    __syncthreads();
    bf16_t* dst = xvT + ((size_t)b * DD + (size_t)dt * 64) * NN + (size_t)nt * 64;
#pragma unroll
    for (int j = 0; j < 2; ++j) {
        int lin = j * 256 + t;
        int dl = lin >> 3;
        int nc = (lin & 7) * 8;
        bf16x8 v;
#pragma unroll
        for (int jj = 0; jj < 8; ++jj) v[jj] = (bf16_t)tile[nc + jj][dl];
        *(bf16x8*)(dst + (size_t)dl * NN + nc) = v;
    }
}

__device__ __forceinline__ void load_lds16(const void* g, void* l) {
    __builtin_amdgcn_global_load_lds((const __attribute__((address_space(1))) uint32_t*)g,
                                     (__attribute__((address_space(3))) uint32_t*)l,
                                     16, 0, 0);
}

// ---------------- Kernel 3: flash attention, 32x32 MFMA, KBLK=64 ----------------
// Waves: w = (qg<<1)|kh for QK (qg = q 32-row half, kh = key 32-col half);
//        w = ds (d-slice of 96) for PV.
// K LDS (48KB): fragment-linear: 16B slot index = (c2h*64 + key), c2h = chunk*2+hi.
// P LDS (16KB): row q stride 256B, byte = q*256 + ((k*2) ^ ((q&15)<<4))  [swizzled].
// V: direct global->reg B-fragments from xvT (full L2-line use; LDS staging had 1x reuse).
template <bool SPLIT>
__global__ __launch_bounds__(256, 2) void attn_kernel(const float* __restrict__ x,
                                                      const bf16_t* __restrict__ xn,
                                                      const bf16_t* __restrict__ xvT,
                                                      float* __restrict__ out,
                                                      float* __restrict__ Opart,
                                                      float* __restrict__ lpart) {
    constexpr int TPS = SPLIT ? (NT / 2) : NT;
    __shared__ __align__(16) char Ks[49152];      // K tile, fragment-linear
    __shared__ __align__(16) char Pb[16384];      // P, swizzled rows of 256B

    const int tid = threadIdx.x;
    const int w = tid >> 6, l = tid & 63;
    const int l31 = l & 31, hi = l >> 5;
    const int qg = w >> 1, kh = w & 1;

    const int bid = blockIdx.x;
    int b, qi, s_idx;
    if (SPLIT) {  // xcd = bid&7 -> (batch, split); 3MB K/V stream per XCD L2
        b = (bid & 7) >> 1; s_idx = bid & 1; qi = bid >> 3;
    } else {
        b = (bid >> 1) & 3; s_idx = 0; qi = (bid >> 3) | ((bid & 1) << 5);
    }
    const int kt0 = s_idx * TPS;
    const int qrow0 = b * NN + qi * 64;

    const char* xnb  = (const char*)xn;
    const char* xvTb = (const char*)xvT;
    char* Ksb = (char*)Ks;
    char* Pbb = (char*)Pb;

    // --- Q fragments in regs: 24 chunks of K=16 (rows qg*32+l31) ---
    const bf16_t* qp = xn + (size_t)(qrow0 + qg * 32 + l31) * DD + hi * 8;
    bf16x8 qf[24];
#pragma unroll
    for (int c = 0; c < 24; ++c) qf[c] = *(const bf16x8*)(qp + c * 16);

    f32x16 O0, O1, O2, O3, O4, O5;   // O(3*g2+dt): rows g2*32.., cols w*96+dt*32..
    O0 = 0.f; O1 = 0.f; O2 = 0.f; O3 = 0.f; O4 = 0.f; O5 = 0.f;
    float lacc = 0.f;                 // P row-sum partial (row tid>>2, keys (tid&3)*16..+16)

#define STAGE_K(KT) { \
    const size_t kg = ((size_t)b * NN + (size_t)(KT) * KBLK) * (DD * 2); \
    _Pragma("unroll") \
    for (int i = 0; i < 12; ++i) { \
        int idx = i * 256 + tid; int key = idx & 63; int c2h = idx >> 6; \
        load_lds16(xnb + kg + (size_t)key * (DD * 2) + c2h * 16, \
                   (void*)(Ksb + (size_t)(i * 256 + (w << 6)) * 16)); \
    } }

    STAGE_K(kt0);

    // per-lane constants
    const char* kB = Ksb + (size_t)(hi * 64 + kh * 32 + l31) * 16;       // QK B-frag base
    const int psw = (l31 & 15) << 4;                                     // P read swizzle
    const int rsrow = tid >> 2, rsseg = tid & 3;                         // row-sum role
    const int rswz = (rsrow & 15) << 4;
    const int kcol2 = (kh * 32 + l31) * 2;                               // P write column byte

    for (int t = 0; t < TPS; ++t) {
        const int kt = kt0 + t;
        // --- top barrier: K[t] staging complete everywhere ---
        asm volatile("s_waitcnt vmcnt(0)" ::: "memory");
        __builtin_amdgcn_sched_barrier(0);
        __builtin_amdgcn_s_barrier();
        __builtin_amdgcn_sched_barrier(0);

        // --- V B-fragments direct from global (consumed in PV) ---
        bf16x8 vf[3][4];
        {
            const char* vB = xvTb + (((size_t)(b * DD + w * 96 + l31) * NN)
                                     + (size_t)kt * KBLK + hi * 8) * 2;
#pragma unroll
            for (int dt = 0; dt < 3; ++dt)
#pragma unroll
                for (int kc = 0; kc < 4; ++kc)
                    vf[dt][kc] = *(const bf16x8*)(vB + (size_t)dt * 32 * (NN * 2) + kc * 32);
        }

        // --- QK^T: S[32q x 32k] = 24 x mfma_32x32x16 ---
        f32x16 s = 0.f;
#pragma unroll
        for (int c = 0; c < 24; ++c) {
            bf16x8 kf = *(const bf16x8*)(kB + c * 2048);
            s = __builtin_amdgcn_mfma_f32_32x32x16_bf16(qf[c], kf, s, 0, 0, 0);
        }

        __builtin_amdgcn_sched_barrier(0);
        __builtin_amdgcn_s_barrier();      // QK reads retired -> K buf reusable
        __builtin_amdgcn_sched_barrier(0);

        // --- issue K[t+1] staging (completes by next top barrier) ---
        {
            int ktn = kt + 1; if (ktn > NT - 1) ktn = NT - 1;
            STAGE_K(ktn);
        }
        __builtin_amdgcn_sched_barrier(0);

        // --- fixed-max softmax + P writes (swizzled) ---
#pragma unroll
        for (int r = 0; r < 16; ++r) {
            float p = exp2f(fmaf(s[r], SCALEC, -SCALEC));
            int q = qg * 32 + 4 * hi + (r & 3) + 8 * (r >> 2);
            int off = q * 256 + (kcol2 ^ ((q & 15) << 4));
            *(bf16_t*)(Pbb + off) = (bf16_t)p;
        }
        asm volatile("s_waitcnt lgkmcnt(0)" ::: "memory");
        __builtin_amdgcn_sched_barrier(0);
        __builtin_amdgcn_s_barrier();      // P visible block-wide
        __builtin_amdgcn_sched_barrier(0);

        // --- P row-sum (denominator): thread sums P[rsrow][rsseg*16..+16] ---
        {
            const char* rb = Pbb + rsrow * 256;
            bf16x8 a = *(const bf16x8*)(rb + ((rsseg * 32) ^ rswz));
            bf16x8 c = *(const bf16x8*)(rb + ((rsseg * 32 + 16) ^ rswz));
            float ps = 0.f;
#pragma unroll
            for (int e = 0; e < 8; ++e) ps += (float)a[e] + (float)c[e];
            lacc += ps;
        }

        // --- PV: wave = d-slice ds=w (96 cols); A reuse 3x, B reuse 2x ---
#pragma unroll
        for (int g2 = 0; g2 < 2; ++g2) {
            const char* paB = Pbb + (g2 * 32 + l31) * 256;
#pragma unroll
            for (int kc = 0; kc < 4; ++kc) {
                bf16x8 pa = *(const bf16x8*)(paB + ((kc * 32 + hi * 16) ^ psw));
                if (g2 == 0) {
                    O0 = __builtin_amdgcn_mfma_f32_32x32x16_bf16(pa, vf[0][kc], O0, 0, 0, 0);
                    O1 = __builtin_amdgcn_mfma_f32_32x32x16_bf16(pa, vf[1][kc], O1, 0, 0, 0);
                    O2 = __builtin_amdgcn_mfma_f32_32x32x16_bf16(pa, vf[2][kc], O2, 0, 0, 0);
                } else {
                    O3 = __builtin_amdgcn_mfma_f32_32x32x16_bf16(pa, vf[0][kc], O3, 0, 0, 0);
                    O4 = __builtin_amdgcn_mfma_f32_32x32x16_bf16(pa, vf[1][kc], O4, 0, 0, 0);
                    O5 = __builtin_amdgcn_mfma_f32_32x32x16_bf16(pa, vf[2][kc], O5, 0, 0, 0);
                }
            }
        }
    }
#undef STAGE_K

    // --- finalize denominator: 4 threads per row ---
    lacc += __shfl_xor(lacc, 1);
    lacc += __shfl_xor(lacc, 2);          // all 4 threads of a row hold the row sum

    if (SPLIT) {
        if ((tid & 3) == 0) lpart[(size_t)s_idx * NROWS + qrow0 + rsrow] = lacc;
        float* Ob = Opart + (size_t)s_idx * NROWS * DD;
        const f32x16* Os[6] = {&O0, &O1, &O2, &O3, &O4, &O5};
#pragma unroll
        for (int g2 = 0; g2 < 2; ++g2) {
#pragma unroll
            for (int dt = 0; dt < 3; ++dt) {
                const f32x16& Ot = *Os[g2 * 3 + dt];
                int dcol = w * 96 + dt * 32 + l31;
#pragma unroll
                for (int r = 0; r < 16; ++r) {
                    int q = g2 * 32 + 4 * hi + (r & 3) + 8 * (r >> 2);
                    Ob[(size_t)(qrow0 + q) * DD + dcol] = Ot[r];
                }
            }
        }
    } else {
        __builtin_amdgcn_s_barrier();
        float* lb = (float*)Pbb;           // P dead; reuse as l buffer
        if ((tid & 3) == 0) lb[rsrow] = lacc;
        asm volatile("s_waitcnt lgkmcnt(0)" ::: "memory");
        __builtin_amdgcn_s_barrier();
        const f32x16* Os[6] = {&O0, &O1, &O2, &O3, &O4, &O5};
#pragma unroll
        for (int g2 = 0; g2 < 2; ++g2) {
#pragma unroll
            for (int dt = 0; dt < 3; ++dt) {
                const f32x16& Ot = *Os[g2 * 3 + dt];
                int dcol = w * 96 + dt * 32 + l31;
#pragma unroll
                for (int r = 0; r < 16; ++r) {
                    int q = g2 * 32 + 4 * hi + (r & 3) + 8 * (r >> 2);
                    size_t idx = (size_t)(qrow0 + q) * DD + dcol;
                    out[idx] = x[idx] + Ot[r] * (0.3f / lb[q]);
                }
            }
        }
    }
}

// ---------------- Kernel 4: merge 2 splits + residual ----------------
__global__ __launch_bounds__(256) void merge_kernel(const float* __restrict__ x,
                                                    const float* __restrict__ Opart,
                                                    const float* __restrict__ lpart,
                                                    float* __restrict__ out) {
    int row  = blockIdx.x * 4 + (threadIdx.x >> 6);
    int lane = threadIdx.x & 63;
    float lsum = lpart[row] + lpart[NROWS + row];
    float inv = 0.3f / lsum;
    size_t base = (size_t)row * DD;
    const float* O0 = Opart + base;
    const float* O1 = Opart + (size_t)NROWS * DD + base;
#pragma unroll
    for (int j = 0; j < 6; ++j) {
        int d = lane + j * 64;
        out[base + d] = x[base + d] + (O0[d] + O1[d]) * inv;
    }
}

extern "C" void kernel_launch(void* const* d_in, const int* in_sizes, int n_in,
                              void* d_out, int out_size, void* d_ws, size_t ws_size,
                              hipStream_t stream) {
    const float* x = (const float*)d_in[0];
    float* out = (float*)d_out;
    char* ws = (char*)d_ws;

    const size_t xn_bytes = (size_t)BB * NN * DD * 2;           // 12.58 MB
    bf16_t* xn  = (bf16_t*)ws;
    bf16_t* xvT = (bf16_t*)(ws + xn_bytes);
    float* Opart = (float*)(ws + 2 * xn_bytes);
    const size_t Opart_bytes = (size_t)2 * NROWS * DD * 4;      // 50.3 MB
    float* lpart = (float*)(ws + 2 * xn_bytes + Opart_bytes);
    const size_t need2 = 2 * xn_bytes + Opart_bytes + (size_t)2 * NROWS * 4;

    norm_kernel<<<(BB * NN) / 4, 256, 0, stream>>>(x, xn);
    transpose_kernel<<<BB * (NN / 64) * (DD / 64), 256, 0, stream>>>(x, xvT);
    if (ws_size >= need2) {
        attn_kernel<true><<<512, 256, 0, stream>>>(x, xn, xvT, out, Opart, lpart);
        merge_kernel<<<NROWS / 4, 256, 0, stream>>>(x, Opart, lpart, out);
    } else {
        attn_kernel<false><<<256, 256, 0, stream>>>(x, xn, xvT, out, nullptr, nullptr);
    }
}

// Round 5
// 342.888 us; speedup vs baseline: 2.3563x; 2.3563x over previous
//
#include <hip/hip_runtime.h>
#include <hip/hip_bf16.h>
#include <stdint.h>

typedef __bf16 bf16_t;
typedef __bf16 bf16x8 __attribute__((ext_vector_type(8)));
typedef float f32x16 __attribute__((ext_vector_type(16)));

#define BB 4
#define NN 4096
#define DD 384
#define KBLK 64
#define NT (NN / KBLK)             // 64 kv tiles of 64 keys
#define NROWS (BB * NN)            // 16384
#define SCALEC 20.609929155556627f // log2(e)/0.07 ; also the fixed softmax max

// ---------------- Kernel 1: row-normalize -> bf16 ----------------
__global__ __launch_bounds__(256) void norm_kernel(const float* __restrict__ x,
                                                   bf16_t* __restrict__ xn) {
    int row  = blockIdx.x * 4 + (threadIdx.x >> 6);
    int lane = threadIdx.x & 63;
    const float* xr = x + (size_t)row * DD;
    float v[6];
    float ss = 0.f;
#pragma unroll
    for (int j = 0; j < 6; ++j) { v[j] = xr[lane + j * 64]; ss += v[j] * v[j]; }
#pragma unroll
    for (int m = 1; m < 64; m <<= 1) ss += __shfl_xor(ss, m);
    float inv = 1.0f / fmaxf(sqrtf(ss), 1e-12f);
    bf16_t* o = xn + (size_t)row * DD;
#pragma unroll
    for (int j = 0; j < 6; ++j) o[lane + j * 64] = (bf16_t)(v[j] * inv);
}

// ---------------- Kernel 2: transpose-cast x -> xvT (B, D, N) bf16 ----------------
__global__ __launch_bounds__(256) void transpose_kernel(const float* __restrict__ x,
                                                        bf16_t* __restrict__ xvT) {
    int bid = blockIdx.x;
    int dt = bid % (DD / 64);                 // 6
    int nt = (bid / (DD / 64)) % (NN / 64);   // 64
    int b  = bid / ((DD / 64) * (NN / 64));
    __shared__ float tile[64][65];
    int t = threadIdx.x;
    const float* src = x + ((size_t)b * NN + (size_t)nt * 64) * DD + dt * 64;
#pragma unroll
    for (int j = 0; j < 4; ++j) {
        int lin = j * 256 + t;
        int nl = lin >> 4;
        int dc = (lin & 15) * 4;
        const float4 f = *(const float4*)(src + (size_t)nl * DD + dc);
        tile[nl][dc + 0] = f.x; tile[nl][dc + 1] = f.y;
        tile[nl][dc + 2] = f.z; tile[nl][dc + 3] = f.w;
    }
    __syncthreads();
    bf16_t* dst = xvT + ((size_t)b * DD + (size_t)dt * 64) * NN + (size_t)nt * 64;
#pragma unroll
    for (int j = 0; j < 2; ++j) {
        int lin = j * 256 + t;
        int dl = lin >> 3;
        int nc = (lin & 7) * 8;
        bf16x8 v;
#pragma unroll
        for (int jj = 0; jj < 8; ++jj) v[jj] = (bf16_t)tile[nc + jj][dl];
        *(bf16x8*)(dst + (size_t)dl * NN + nc) = v;
    }
}

__device__ __forceinline__ void load_lds16(const void* g, void* l) {
    __builtin_amdgcn_global_load_lds((const __attribute__((address_space(1))) uint32_t*)g,
                                     (__attribute__((address_space(3))) uint32_t*)l,
                                     16, 0, 0);
}

// ---------------- Kernel 3: flash attention, 32x32 MFMA, KBLK=64 ----------------
// Waves: w = (qg<<1)|kh for QK (qg = q 32-row half, kh = key 32-col half);
//        w = d-slice of 96 for PV.
// K LDS (48KB) fragment-linear: 16B slot = (c2h*64 + key), c2h = chunk*2+hi.
// P LDS (16KB): row q stride 256B, byte = q*256 + ((k*2) ^ ((q&15)<<4)).
// V: direct global->reg, pipelined in 12-VGPR slices (NO large vf array -> no spill).
template <bool SPLIT>
__global__ __launch_bounds__(256, 2) void attn_kernel(const float* __restrict__ x,
                                                      const bf16_t* __restrict__ xn,
                                                      const bf16_t* __restrict__ xvT,
                                                      float* __restrict__ out,
                                                      float* __restrict__ Opart,
                                                      float* __restrict__ lpart) {
    constexpr int TPS = SPLIT ? (NT / 2) : NT;
    __shared__ __align__(16) char Ks[49152];      // K tile, fragment-linear
    __shared__ __align__(16) char Pb[16384];      // P, swizzled rows of 256B

    const int tid = threadIdx.x;
    const int w = tid >> 6, l = tid & 63;
    const int l31 = l & 31, hi = l >> 5;
    const int qg = w >> 1, kh = w & 1;

    const int bid = blockIdx.x;
    int b, qi, s_idx;
    if (SPLIT) {  // xcd = bid&7 -> (batch, split)
        b = (bid & 7) >> 1; s_idx = bid & 1; qi = bid >> 3;
    } else {
        b = (bid >> 1) & 3; s_idx = 0; qi = (bid >> 3) | ((bid & 1) << 5);
    }
    const int kt0 = s_idx * TPS;
    const int qrow0 = b * NN + qi * 64;

    const char* xnb  = (const char*)xn;
    const char* xvTb = (const char*)xvT;
    char* Ksb = (char*)Ks;
    char* Pbb = (char*)Pb;

    // --- Q fragments in regs: 24 chunks of K=16 (rows qg*32+l31) ---
    const bf16_t* qp = xn + (size_t)(qrow0 + qg * 32 + l31) * DD + hi * 8;
    bf16x8 qf[24];
#pragma unroll
    for (int c = 0; c < 24; ++c) qf[c] = *(const bf16x8*)(qp + c * 16);

    f32x16 O0, O1, O2, O3, O4, O5;   // O(3*g2+dt): rows g2*32.., cols w*96+dt*32..
    O0 = 0.f; O1 = 0.f; O2 = 0.f; O3 = 0.f; O4 = 0.f; O5 = 0.f;
    float lacc = 0.f;                 // row-sum partial (row tid>>2, keys (tid&3)*16..+16)

#define STAGE_K(KT) { \
    const size_t kg = ((size_t)b * NN + (size_t)(KT) * KBLK) * (DD * 2); \
    _Pragma("unroll") \
    for (int i = 0; i < 12; ++i) { \
        int idx = i * 256 + tid; int key = idx & 63; int c2h = idx >> 6; \
        load_lds16(xnb + kg + (size_t)key * (DD * 2) + c2h * 16, \
                   (void*)(Ksb + (size_t)(i * 256 + (w << 6)) * 16)); \
    } }

    STAGE_K(kt0);

    // per-lane constants
    const char* kB = Ksb + (size_t)(hi * 64 + kh * 32 + l31) * 16;       // QK B-frag base
    const int psw = (l31 & 15) << 4;                                     // P read swizzle
    const int rsrow = tid >> 2, rsseg = tid & 3;                         // row-sum role
    const int rswz = (rsrow & 15) << 4;
    const int kcol2 = (kh * 32 + l31) * 2;                               // P write column byte

#define VLD(DST, KC) { \
    _Pragma("unroll") \
    for (int dt = 0; dt < 3; ++dt) \
        DST[dt] = *(const bf16x8*)(vB + (size_t)dt * 32 * (NN * 2) + (KC) * 32); }

#define PV_STEP(VF, KC) { \
    bf16x8 pa0 = *(const bf16x8*)(Pbb + (l31) * 256 + (((KC) * 32 + hi * 16) ^ psw)); \
    bf16x8 pa1 = *(const bf16x8*)(Pbb + (32 + l31) * 256 + (((KC) * 32 + hi * 16) ^ psw)); \
    O0 = __builtin_amdgcn_mfma_f32_32x32x16_bf16(pa0, VF[0], O0, 0, 0, 0); \
    O1 = __builtin_amdgcn_mfma_f32_32x32x16_bf16(pa0, VF[1], O1, 0, 0, 0); \
    O2 = __builtin_amdgcn_mfma_f32_32x32x16_bf16(pa0, VF[2], O2, 0, 0, 0); \
    O3 = __builtin_amdgcn_mfma_f32_32x32x16_bf16(pa1, VF[0], O3, 0, 0, 0); \
    O4 = __builtin_amdgcn_mfma_f32_32x32x16_bf16(pa1, VF[1], O4, 0, 0, 0); \
    O5 = __builtin_amdgcn_mfma_f32_32x32x16_bf16(pa1, VF[2], O5, 0, 0, 0); }

    for (int t = 0; t < TPS; ++t) {
        const int kt = kt0 + t;
        const char* vB = xvTb + (((size_t)(b * DD + w * 96 + l31) * NN)
                                 + (size_t)kt * KBLK + hi * 8) * 2;
        // --- top barrier: K[t] staging complete everywhere ---
        asm volatile("s_waitcnt vmcnt(0)" ::: "memory");
        __builtin_amdgcn_sched_barrier(0);
        __builtin_amdgcn_s_barrier();
        __builtin_amdgcn_sched_barrier(0);

        // --- QK^T: S[32q x 32k] = 24 x mfma_32x32x16 ---
        f32x16 s = 0.f;
#pragma unroll
        for (int c = 0; c < 24; ++c) {
            bf16x8 kf = *(const bf16x8*)(kB + c * 2048);
            s = __builtin_amdgcn_mfma_f32_32x32x16_bf16(qf[c], kf, s, 0, 0, 0);
        }

        __builtin_amdgcn_sched_barrier(0);
        __builtin_amdgcn_s_barrier();      // QK reads retired -> K buf reusable
        __builtin_amdgcn_sched_barrier(0);

        // --- issue K[t+1] staging (gload_lds: zero VGPR cost) ---
        {
            int ktn = kt + 1; if (ktn > NT - 1) ktn = NT - 1;
            STAGE_K(ktn);
        }
        __builtin_amdgcn_sched_barrier(0);

        // --- V slice kc0 issued here: covered by softmax+P-write+barrier ---
        bf16x8 vfA[3], vfB[3];
        VLD(vfA, 0);

        // --- fixed-max softmax + P writes (swizzled) ---
#pragma unroll
        for (int r = 0; r < 16; ++r) {
            float p = exp2f(fmaf(s[r], SCALEC, -SCALEC));
            int q = qg * 32 + 4 * hi + (r & 3) + 8 * (r >> 2);
            int off = q * 256 + (kcol2 ^ ((q & 15) << 4));
            *(bf16_t*)(Pbb + off) = (bf16_t)p;
        }
        asm volatile("s_waitcnt lgkmcnt(0)" ::: "memory");
        __builtin_amdgcn_sched_barrier(0);
        __builtin_amdgcn_s_barrier();      // P visible block-wide
        __builtin_amdgcn_sched_barrier(0);

        // --- V slice kc1; then denominator row-sum (covers kc1 latency) ---
        VLD(vfB, 1);
        {
            const char* rb = Pbb + rsrow * 256;
            bf16x8 a = *(const bf16x8*)(rb + ((rsseg * 32) ^ rswz));
            bf16x8 c = *(const bf16x8*)(rb + ((rsseg * 32 + 16) ^ rswz));
            float ps = 0.f;
#pragma unroll
            for (int e = 0; e < 8; ++e) ps += (float)a[e] + (float)c[e];
            lacc += ps;
        }

        // --- PV pipelined: compute kc while loading kc+2 ---
        PV_STEP(vfA, 0);
        VLD(vfA, 2);
        PV_STEP(vfB, 1);
        VLD(vfB, 3);
        PV_STEP(vfA, 2);
        PV_STEP(vfB, 3);
    }
#undef STAGE_K
#undef VLD
#undef PV_STEP

    // --- finalize denominator: 4 threads per row ---
    lacc += __shfl_xor(lacc, 1);
    lacc += __shfl_xor(lacc, 2);          // all 4 threads of a row hold the row sum

    if (SPLIT) {
        if ((tid & 3) == 0) lpart[(size_t)s_idx * NROWS + qrow0 + rsrow] = lacc;
        float* Ob = Opart + (size_t)s_idx * NROWS * DD;
        const f32x16* Os[6] = {&O0, &O1, &O2, &O3, &O4, &O5};
#pragma unroll
        for (int g2 = 0; g2 < 2; ++g2) {
#pragma unroll
            for (int dt = 0; dt < 3; ++dt) {
                const f32x16& Ot = *Os[g2 * 3 + dt];
                int dcol = w * 96 + dt * 32 + l31;
#pragma unroll
                for (int r = 0; r < 16; ++r) {
                    int q = g2 * 32 + 4 * hi + (r & 3) + 8 * (r >> 2);
                    Ob[(size_t)(qrow0 + q) * DD + dcol] = Ot[r];
                }
            }
        }
    } else {
        __builtin_amdgcn_s_barrier();
        float* lb = (float*)Pbb;           // P dead; reuse as l buffer
        if ((tid & 3) == 0) lb[rsrow] = lacc;
        asm volatile("s_waitcnt lgkmcnt(0)" ::: "memory");
        __builtin_amdgcn_s_barrier();
        const f32x16* Os[6] = {&O0, &O1, &O2, &O3, &O4, &O5};
#pragma unroll
        for (int g2 = 0; g2 < 2; ++g2) {
#pragma unroll
            for (int dt = 0; dt < 3; ++dt) {
                const f32x16& Ot = *Os[g2 * 3 + dt];
                int dcol = w * 96 + dt * 32 + l31;
#pragma unroll
                for (int r = 0; r < 16; ++r) {
                    int q = g2 * 32 + 4 * hi + (r & 3) + 8 * (r >> 2);
                    size_t idx = (size_t)(qrow0 + q) * DD + dcol;
                    out[idx] = x[idx] + Ot[r] * (0.3f / lb[q]);
                }
            }
        }
    }
}

// ---------------- Kernel 4: merge 2 splits + residual ----------------
__global__ __launch_bounds__(256) void merge_kernel(const float* __restrict__ x,
                                                    const float* __restrict__ Opart,
                                                    const float* __restrict__ lpart,
                                                    float* __restrict__ out) {
    int row  = blockIdx.x * 4 + (threadIdx.x >> 6);
    int lane = threadIdx.x & 63;
    float lsum = lpart[row] + lpart[NROWS + row];
    float inv = 0.3f / lsum;
    size_t base = (size_t)row * DD;
    const float* O0 = Opart + base;
    const float* O1 = Opart + (size_t)NROWS * DD + base;
#pragma unroll
    for (int j = 0; j < 6; ++j) {
        int d = lane + j * 64;
        out[base + d] = x[base + d] + (O0[d] + O1[d]) * inv;
    }
}

extern "C" void kernel_launch(void* const* d_in, const int* in_sizes, int n_in,
                              void* d_out, int out_size, void* d_ws, size_t ws_size,
                              hipStream_t stream) {
    const float* x = (const float*)d_in[0];
    float* out = (float*)d_out;
    char* ws = (char*)d_ws;

    const size_t xn_bytes = (size_t)BB * NN * DD * 2;           // 12.58 MB
    bf16_t* xn  = (bf16_t*)ws;
    bf16_t* xvT = (bf16_t*)(ws + xn_bytes);
    float* Opart = (float*)(ws + 2 * xn_bytes);
    const size_t Opart_bytes = (size_t)2 * NROWS * DD * 4;      // 50.3 MB
    float* lpart = (float*)(ws + 2 * xn_bytes + Opart_bytes);
    const size_t need2 = 2 * xn_bytes + Opart_bytes + (size_t)2 * NROWS * 4;

    norm_kernel<<<(BB * NN) / 4, 256, 0, stream>>>(x, xn);
    transpose_kernel<<<BB * (NN / 64) * (DD / 64), 256, 0, stream>>>(x, xvT);
    if (ws_size >= need2) {
        attn_kernel<true><<<512, 256, 0, stream>>>(x, xn, xvT, out, Opart, lpart);
        merge_kernel<<<NROWS / 4, 256, 0, stream>>>(x, Opart, lpart, out);
    } else {
        attn_kernel<false><<<256, 256, 0, stream>>>(x, xn, xvT, out, nullptr, nullptr);
    }
}